// Round 3
// baseline (372.313 us; speedup 1.0000x reference)
//
#include <hip/hip_runtime.h>
#include <math.h>

#define BATCH 64
#define SEQ   4096
#define HID   256
#define NBLK  32                          // S-chunks per batch
#define ROWS_PER_BLK (SEQ / NBLK)         // 128 rows per block
#define THREADS 256
#define GSZ   8                           // lanes per row-group
#define NGRP  (THREADS / GSZ)             // 32 groups -> 32 rows per iter
#define ITERS (ROWS_PER_BLK / NGRP)       // 4 serial iterations
#define VPL   (HID / (GSZ * 4))           // 8 float4 per lane per row

// Single fused kernel: streaming online-softmax pool over trg, then the
// last-arriving block per batch (atomic ticket) runs the combine + MLP.
__global__ __launch_bounds__(THREADS) void pool_fused(
        const float* __restrict__ trg,
        const float* __restrict__ W1,
        const float* __restrict__ b1,
        const float* __restrict__ W2,
        const float* __restrict__ b2,
        float* __restrict__ ws_m,
        float* __restrict__ ws_l,
        float* __restrict__ ws_p,
        unsigned int* __restrict__ ws_cnt,
        float* __restrict__ out) {
    const int b     = blockIdx.x / NBLK;
    const int chunk = blockIdx.x % NBLK;
    const int tid   = threadIdx.x;
    const int gid   = tid >> 3;           // 0..31: row-group id
    const int sub   = tid & 7;            // lane within group

    const float* base = trg + ((size_t)b * SEQ + (size_t)chunk * ROWS_PER_BLK) * HID;

    float m = -INFINITY, l = 0.f;
    float4 acc[VPL];
    #pragma unroll
    for (int q = 0; q < VPL; ++q) acc[q] = make_float4(0.f, 0.f, 0.f, 0.f);

    #pragma unroll 1                      // keep VGPR in the 4-waves/SIMD bin
    for (int t = 0; t < ITERS; ++t) {
        const float* rp = base + (size_t)(t * NGRP + gid) * HID + sub * 4;
        float4 v[VPL];
        #pragma unroll
        for (int q = 0; q < VPL; ++q)
            v[q] = *reinterpret_cast<const float4*>(rp + q * (GSZ * 4));

        float ss = 0.f;
        #pragma unroll
        for (int q = 0; q < VPL; ++q)
            ss += v[q].x * v[q].x + v[q].y * v[q].y
                + v[q].z * v[q].z + v[q].w * v[q].w;
        // reduce across the 8-lane group (xor masks < 8 stay in-group)
        ss += __shfl_xor(ss, 1, 64);
        ss += __shfl_xor(ss, 2, 64);
        ss += __shfl_xor(ss, 4, 64);
        const float nrm = sqrtf(ss);      // uniform across the group

        if (nrm > m + 8.f) {              // defer-max: rare after first iter
            const float sc = __expf(m - nrm);  // 0 on first iter (m=-inf)
            l *= sc;
            #pragma unroll
            for (int q = 0; q < VPL; ++q) {
                acc[q].x *= sc; acc[q].y *= sc;
                acc[q].z *= sc; acc[q].w *= sc;
            }
            m = nrm;
        }
        const float p = __expf(nrm - m);  // <= e^8, fp32-safe
        l += p;
        #pragma unroll
        for (int q = 0; q < VPL; ++q) {
            acc[q].x = fmaf(p, v[q].x, acc[q].x);
            acc[q].y = fmaf(p, v[q].y, acc[q].y);
            acc[q].z = fmaf(p, v[q].z, acc[q].z);
            acc[q].w = fmaf(p, v[q].w, acc[q].w);
        }
    }

    // ---- block combine across 32 groups ----
    __shared__ float s_m[NGRP];           // also reused for chunk maxes (NBLK==NGRP)
    __shared__ float s_l[NGRP];
    __shared__ float s_p[NGRP][HID];      // 32 KiB
    __shared__ float s_fin[HID];
    __shared__ float s_red[4];
    __shared__ unsigned int s_ticket;

    if (sub == 0) { s_m[gid] = m; }
    __syncthreads();
    float m_blk = s_m[0];
    #pragma unroll
    for (int g = 1; g < NGRP; ++g) m_blk = fmaxf(m_blk, s_m[g]);
    const float sc = __expf(m - m_blk);   // group-uniform
    if (sub == 0) s_l[gid] = l * sc;
    #pragma unroll
    for (int q = 0; q < VPL; ++q) {
        float4 a = acc[q];
        a.x *= sc; a.y *= sc; a.z *= sc; a.w *= sc;
        *reinterpret_cast<float4*>(&s_p[gid][q * (GSZ * 4) + sub * 4]) = a;
    }
    __syncthreads();

    const int j = tid;                    // output column 0..255
    float pj = 0.f;
    #pragma unroll
    for (int g = 0; g < NGRP; ++g) pj += s_p[g][j];
    const int pidx = b * NBLK + chunk;
    ws_p[(size_t)pidx * HID + j] = pj;
    if (j == 0) {
        ws_m[pidx] = m_blk;
        float lt = 0.f;
        #pragma unroll
        for (int g = 0; g < NGRP; ++g) lt += s_l[g];
        ws_l[pidx] = lt;
    }

    // ---- last block per batch does the combine + MLP ----
    __threadfence();                      // release: flush partials device-scope
    __syncthreads();
    if (tid == 0) s_ticket = atomicAdd(&ws_cnt[b], 1u);
    __syncthreads();
    if (s_ticket != NBLK - 1) return;
    __threadfence();                      // acquire: see other XCDs' partials

    if (j < NBLK) {                       // reuse s_m/s_l for chunk partials
        s_m[j] = ws_m[b * NBLK + j];
        s_l[j] = ws_l[b * NBLK + j];
    }
    __syncthreads();
    float mm = s_m[0];
    #pragma unroll
    for (int i = 1; i < NBLK; ++i) mm = fmaxf(mm, s_m[i]);
    float lt = 0.f;
    pj = 0.f;
    #pragma unroll 8
    for (int i = 0; i < NBLK; ++i) {
        const float c = __expf(s_m[i] - mm);
        lt += s_l[i] * c;
        pj += ws_p[(size_t)(b * NBLK + i) * HID + j] * c;
    }
    s_fin[j] = pj / lt;                   // pooled[j]
    __syncthreads();

    // FC1 column j: h = relu(sum_k pooled[k] * W1[k][j] + b1[j])
    float h = b1[j];
    #pragma unroll 8
    for (int k = 0; k < HID; ++k)
        h = fmaf(s_fin[k], W1[k * HID + j], h);
    h = fmaxf(h, 0.f);

    // FC2: out[b] = sum_j h[j] * W2[j] + b2
    float v = h * W2[j];
    #pragma unroll
    for (int off = 32; off > 0; off >>= 1)
        v += __shfl_xor(v, off, 64);
    if ((j & 63) == 0) s_red[j >> 6] = v;
    __syncthreads();
    if (j == 0)
        out[b] = s_red[0] + s_red[1] + s_red[2] + s_red[3] + b2[0];
}

extern "C" void kernel_launch(void* const* d_in, const int* in_sizes, int n_in,
                              void* d_out, int out_size, void* d_ws, size_t ws_size,
                              hipStream_t stream) {
    const float* trg = (const float*)d_in[0];
    // d_in[1] = src: unused (n_layers = 0)
    const float* W1  = (const float*)d_in[2];
    const float* b1  = (const float*)d_in[3];
    const float* W2  = (const float*)d_in[4];
    const float* b2  = (const float*)d_in[5];
    float* out = (float*)d_out;

    // Workspace: cnt[B] | m[B*NBLK] | l[B*NBLK] | pooled[B*NBLK*HID]
    unsigned int* ws_cnt = (unsigned int*)d_ws;
    float* ws_m = (float*)(ws_cnt + BATCH);
    float* ws_l = ws_m + BATCH * NBLK;
    float* ws_p = ws_l + BATCH * NBLK;

    // Zero the per-batch tickets every call (graph-capture-safe memset node).
    hipMemsetAsync(ws_cnt, 0, BATCH * sizeof(unsigned int), stream);

    pool_fused<<<dim3(BATCH * NBLK), THREADS, 0, stream>>>(
        trg, W1, b1, W2, b2, ws_m, ws_l, ws_p, ws_cnt, out);
}

// Round 4
// 58.069 us; speedup vs baseline: 6.4116x; 6.4116x over previous
//
#include <hip/hip_runtime.h>
#include <math.h>

#define BATCH 64
#define SEQ   4096
#define HID   256
#define NBLK  32                          // S-chunks per batch
#define ROWS_PER_BLK (SEQ / NBLK)         // 128 rows per block
#define THREADS 256
#define NWAVE (THREADS / 64)
#define GSZ   8                           // lanes per row-group
#define NGRP  (THREADS / GSZ)             // 32 groups -> 32 rows per iter
#define ITERS (ROWS_PER_BLK / NGRP)       // 4 serial iterations
#define VPL   (HID / (GSZ * 4))           // 8 float4 per lane per row

// Kernel 1: single streaming pass over trg. Each 8-lane group owns one row
// per iteration (8 float4 loads/lane). Online softmax with defer-max.
__global__ __launch_bounds__(THREADS) void pool_pass(
        const float* __restrict__ trg,
        float* __restrict__ ws_m,
        float* __restrict__ ws_l,
        float* __restrict__ ws_p) {
    const int b     = blockIdx.x / NBLK;
    const int chunk = blockIdx.x % NBLK;
    const int tid   = threadIdx.x;
    const int gid   = tid >> 3;           // 0..31: row-group id
    const int sub   = tid & 7;            // lane within group

    const float* base = trg + ((size_t)b * SEQ + (size_t)chunk * ROWS_PER_BLK) * HID;

    float m = -INFINITY, l = 0.f;
    float4 acc[VPL];
    #pragma unroll
    for (int q = 0; q < VPL; ++q) acc[q] = make_float4(0.f, 0.f, 0.f, 0.f);

    #pragma unroll 1                      // stay in the 8-waves/SIMD VGPR bin
    for (int t = 0; t < ITERS; ++t) {
        const float* rp = base + (size_t)(t * NGRP + gid) * HID + sub * 4;
        float4 v[VPL];
        #pragma unroll
        for (int q = 0; q < VPL; ++q)
            v[q] = *reinterpret_cast<const float4*>(rp + q * (GSZ * 4));

        float ss = 0.f;
        #pragma unroll
        for (int q = 0; q < VPL; ++q)
            ss += v[q].x * v[q].x + v[q].y * v[q].y
                + v[q].z * v[q].z + v[q].w * v[q].w;
        // reduce across the 8-lane group (xor masks < 8 stay in-group)
        ss += __shfl_xor(ss, 1, 64);
        ss += __shfl_xor(ss, 2, 64);
        ss += __shfl_xor(ss, 4, 64);
        const float nrm = sqrtf(ss);      // uniform across the group

        if (nrm > m + 8.f) {              // defer-max: rare after first iter
            const float sc = __expf(m - nrm);  // 0 on first iter (m=-inf)
            l *= sc;
            #pragma unroll
            for (int q = 0; q < VPL; ++q) {
                acc[q].x *= sc; acc[q].y *= sc;
                acc[q].z *= sc; acc[q].w *= sc;
            }
            m = nrm;
        }
        const float p = __expf(nrm - m);  // <= e^8, fp32-safe
        l += p;
        #pragma unroll
        for (int q = 0; q < VPL; ++q) {
            acc[q].x = fmaf(p, v[q].x, acc[q].x);
            acc[q].y = fmaf(p, v[q].y, acc[q].y);
            acc[q].z = fmaf(p, v[q].z, acc[q].z);
            acc[q].w = fmaf(p, v[q].w, acc[q].w);
        }
    }

    // ---- block combine across 32 groups ----
    __shared__ float s_m[NGRP];
    __shared__ float s_l[NGRP];
    __shared__ float s_p[NGRP][HID];      // 32 KiB
    if (sub == 0) s_m[gid] = m;
    __syncthreads();
    float m_blk = s_m[0];
    #pragma unroll
    for (int g = 1; g < NGRP; ++g) m_blk = fmaxf(m_blk, s_m[g]);
    const float sc = __expf(m - m_blk);   // group-uniform
    if (sub == 0) s_l[gid] = l * sc;
    #pragma unroll
    for (int q = 0; q < VPL; ++q) {
        float4 a = acc[q];
        a.x *= sc; a.y *= sc; a.z *= sc; a.w *= sc;
        *reinterpret_cast<float4*>(&s_p[gid][q * (GSZ * 4) + sub * 4]) = a;
    }
    __syncthreads();

    const int j = tid;                    // output column 0..255
    float pj = 0.f;
    #pragma unroll
    for (int g = 0; g < NGRP; ++g) pj += s_p[g][j];
    const int pidx = b * NBLK + chunk;
    ws_p[(size_t)pidx * HID + j] = pj;
    if (j == 0) {
        ws_m[pidx] = m_blk;
        float lt = 0.f;
        #pragma unroll
        for (int g = 0; g < NGRP; ++g) lt += s_l[g];
        ws_l[pidx] = lt;
    }
}

// Kernel 2: combine NBLK partials per batch, normalize, tiny MLP.
__global__ __launch_bounds__(THREADS) void finish_pass(
        const float* __restrict__ ws_m,
        const float* __restrict__ ws_l,
        const float* __restrict__ ws_p,
        const float* __restrict__ W1,
        const float* __restrict__ b1,
        const float* __restrict__ W2,
        const float* __restrict__ b2,
        float* __restrict__ out) {
    const int b = blockIdx.x;
    const int j = threadIdx.x;  // 0..255: owns pooled[j], h[j]

    __shared__ float s_m[NBLK];
    __shared__ float s_l[NBLK];
    __shared__ float s_pooled[HID];
    __shared__ float s_red[NWAVE];

    if (j < NBLK) {
        s_m[j] = ws_m[b * NBLK + j];
        s_l[j] = ws_l[b * NBLK + j];
    }
    __syncthreads();

    float m = s_m[0];
    #pragma unroll
    for (int i = 1; i < NBLK; ++i) m = fmaxf(m, s_m[i]);

    float l = 0.f, pj = 0.f;
    #pragma unroll 8
    for (int i = 0; i < NBLK; ++i) {
        const float sc = __expf(s_m[i] - m);
        l  += s_l[i] * sc;
        pj += ws_p[(size_t)(b * NBLK + i) * HID + j] * sc;
    }
    const float pooled = pj / l;
    s_pooled[j] = pooled;
    __syncthreads();

    // FC1 column j: h = relu(sum_k pooled[k] * W1[k][j] + b1[j])
    float h = b1[j];
    #pragma unroll 8
    for (int k = 0; k < HID; ++k)
        h = fmaf(s_pooled[k], W1[k * HID + j], h);
    h = fmaxf(h, 0.f);

    // FC2: out[b] = sum_j h[j] * W2[j] + b2
    float v = h * W2[j];
    #pragma unroll
    for (int off = 32; off > 0; off >>= 1)
        v += __shfl_xor(v, off, 64);
    if ((j & 63) == 0) s_red[j >> 6] = v;
    __syncthreads();
    if (j == 0)
        out[b] = s_red[0] + s_red[1] + s_red[2] + s_red[3] + b2[0];
}

extern "C" void kernel_launch(void* const* d_in, const int* in_sizes, int n_in,
                              void* d_out, int out_size, void* d_ws, size_t ws_size,
                              hipStream_t stream) {
    const float* trg = (const float*)d_in[0];
    // d_in[1] = src: unused (n_layers = 0)
    const float* W1  = (const float*)d_in[2];
    const float* b1  = (const float*)d_in[3];
    const float* W2  = (const float*)d_in[4];
    const float* b2  = (const float*)d_in[5];
    float* out = (float*)d_out;

    // Workspace layout: m[B*NBLK] | l[B*NBLK] | pooled[B*NBLK*HID]
    float* ws_m = (float*)d_ws;
    float* ws_l = ws_m + BATCH * NBLK;
    float* ws_p = ws_l + BATCH * NBLK;

    pool_pass<<<dim3(BATCH * NBLK), THREADS, 0, stream>>>(trg, ws_m, ws_l, ws_p);
    finish_pass<<<dim3(BATCH), THREADS, 0, stream>>>(ws_m, ws_l, ws_p,
                                                     W1, b1, W2, b2, out);
}